// Round 20
// baseline (220.783 us; speedup 1.0000x reference)
//
#include <hip/hip_runtime.h>
#include <hip/hip_bf16.h>

// ---------------------------------------------------------------------------
// FourDNet forward. Convs = bf16 MFMA implicit GEMM (NHWC). Folded chain:
//   v   = dep @ (W_merge_bot @ W_v) + c0v   [fused INTO conv3]
//   sel = sigmoid(F[:,1:] @ W_big + rowbias[b])  [MFMA hi/lo + fused bw]
// Round 19: r2d rebuilt LDS-resident: block = (ch-sixteenth, b) stages
//   v[b][:,16ch]=32KB into padded vs[512][20] once; 96 gathers/output served
//   from LDS (69TB/s, ~25x lower latency than L2). v read from HBM exactly
//   once. Same FMA chain order -> bit-identical output.
// ---------------------------------------------------------------------------

typedef __attribute__((ext_vector_type(8))) short short8;
typedef __attribute__((ext_vector_type(4))) short shortx4;
typedef __attribute__((ext_vector_type(4))) float floatx4;
typedef __attribute__((ext_vector_type(4))) int intx4;

#define MFMA16(a, b, c) __builtin_amdgcn_mfma_f32_16x16x32_bf16(a, b, c, 0, 0, 0)

// ---- prep_a: [0,72) W_qs, [72,200) W_mv, 200 c0, (200,265) gfeat,
//              [265,553) wt2, [553,1129) wt3 ----
__global__ __launch_bounds__(256) void prep_a(
    const float* __restrict__ W_q, const float* __restrict__ W_sel,
    const float* __restrict__ W_merge, const float* __restrict__ W_v,
    const float* __restrict__ g_depth, const float* __restrict__ b_merge,
    const float* __restrict__ features, const float* __restrict__ W_rg,
    const float* __restrict__ b_rg, const float* __restrict__ c2w,
    const float* __restrict__ c3w,
    float* __restrict__ W_qs, float* __restrict__ W_mv,
    float* __restrict__ c0, float* __restrict__ gfeat,
    __hip_bfloat16* __restrict__ w2t, __hip_bfloat16* __restrict__ w3t)
{
    __shared__ float fr_s[768];
    int bid = blockIdx.x, t = threadIdx.x;
    if (bid < 72) {
        int j = bid;
        float acc = 0.f;
        for (int k = 0; k < 128; ++k)
            acc = fmaf(W_q[t * 128 + k], W_sel[k * 72 + j], acc);
        W_qs[t * 72 + j] = acc;
    } else if (bid < 200) {
        int j = bid - 72;
        if (t < 128) {
            float acc = 0.f;
            for (int k = 0; k < 128; ++k)
                acc = fmaf(W_merge[(128 + t) * 128 + k], W_v[k * 128 + j], acc);
            W_mv[t * 128 + j] = acc;
        }
    } else if (bid == 200) {
        if (t < 128) {
            float acc = b_merge[t];
            for (int k = 0; k < 128; ++k)
                acc = fmaf(g_depth[k], W_merge[k * 128 + t], acc);
            c0[t] = acc;
        }
    } else if (bid < 265) {               // gfeat row = bid-201 (64 rows)
        int row = bid - 201;
        for (int l = t; l < 768; l += 256)
            fr_s[l] = features[(long)row * 129 * 768 + l];
        __syncthreads();
        if (t < 128) {
            float acc = b_rg[t];
            for (int k = 0; k < 768; ++k)
                acc = fmaf(fr_s[k], W_rg[k * 128 + t], acc);
            gfeat[row * 128 + t] = acc;
        }
    } else if (bid < 553) {               // wt2
        int idx = (bid - 265) * 256 + t;
        if (idx < 128 * 576) {
            int oc = idx / 576, k = idx % 576;
            int s = k >> 6, ic = k & 63;
            w2t[idx] = __float2bfloat16(c2w[oc * 576 + ic * 9 + s]);
        }
    } else {                              // wt3
        int idx = (bid - 553) * 256 + t;
        if (idx < 128 * 1152) {
            int oc = idx / 1152, k = idx % 1152;
            int s = k >> 7, ic = k & 127;
            w3t[idx] = __float2bfloat16(c3w[oc * 1152 + ic * 9 + s]);
        }
    }
}

// ---- prep2: W_big [768][72], rowbias [64][72], c0v [128] ----
__global__ __launch_bounds__(256) void prep2_k(
    const float* __restrict__ W_rl, const float* __restrict__ W_qs,
    const float* __restrict__ W_sel, const float* __restrict__ b_rl,
    const float* __restrict__ b_q, const float* __restrict__ b_sel,
    const float* __restrict__ gfeat, const float* __restrict__ c0,
    const float* __restrict__ W_v, const float* __restrict__ b_v,
    float* __restrict__ W_big, float* __restrict__ rowbias,
    float* __restrict__ c0v)
{
    int bid = blockIdx.x, t = threadIdx.x;
    if (bid < 216) {
        int j = bid / 3;
        int i = (bid % 3) * 256 + t;
        float acc = 0.f;
        for (int k = 0; k < 128; ++k)
            acc = fmaf(W_rl[i * 128 + k], W_qs[(128 + k) * 72 + j], acc);
        W_big[i * 72 + j] = acc;
    } else if (bid < 288) {
        int j = bid - 216;
        if (t < 64) {
            float vb = b_sel[j];
            for (int k = 0; k < 128; ++k) {
                vb = fmaf(b_rl[k], W_qs[(128 + k) * 72 + j], vb);
                vb = fmaf(b_q[k], W_sel[k * 72 + j], vb);
            }
            float acc = vb;
            for (int k = 0; k < 128; ++k)
                acc = fmaf(gfeat[t * 128 + k], W_qs[k * 72 + j], acc);
            rowbias[t * 72 + j] = acc;
        }
    } else {
        if (t < 128) {
            float acc = b_v[t];
            for (int k = 0; k < 128; ++k)
                acc = fmaf(c0[k], W_v[k * 128 + t], acc);
            c0v[t] = acc;
        }
    }
}

// ---- prep_b: [0,64) W_mv->hi/lo, [64,304) W_big->hi/lo [80][768] ----
__global__ __launch_bounds__(256) void prep_b(
    const float* __restrict__ W_mv, const float* __restrict__ W_big,
    __hip_bfloat16* __restrict__ Bh, __hip_bfloat16* __restrict__ Bl,
    __hip_bfloat16* __restrict__ Wbh, __hip_bfloat16* __restrict__ Wbl)
{
    int bid = blockIdx.x, t = threadIdx.x;
    if (bid < 64) {
        int idx = bid * 256 + t;          // 16384
        int n = idx >> 7, k = idx & 127;
        float w = W_mv[k * 128 + n];
        __hip_bfloat16 h = __float2bfloat16(w);
        Bh[idx] = h;
        Bl[idx] = __float2bfloat16(w - __bfloat162float(h));
    } else {
        int idx = (bid - 64) * 256 + t;   // 61440
        if (idx < 80 * 768) {
            int n = idx / 768, k = idx - n * 768;
            float w = (n < 72) ? W_big[k * 72 + n] : 0.f;
            __hip_bfloat16 h = __float2bfloat16(w);
            Wbh[idx] = h;
            Wbl[idx] = __float2bfloat16(w - __bfloat162float(h));
        }
    }
}

// conv1: d (64,1,256,128) f32 -> out NHWC (64,128,64,64) bf16. stride2 pad1.
__global__ __launch_bounds__(256) void conv1_k(
    const float* __restrict__ d, const float* __restrict__ w,
    const float* __restrict__ bias, __hip_bfloat16* __restrict__ out)
{
    __shared__ float in_s[9][130];
    __shared__ float ws_[576];
    __shared__ float bs_[64];
    int tid = threadIdx.x;
    int ohg = blockIdx.x & 31;
    int b   = blockIdx.x >> 5;
    int oh0 = ohg * 4;

    for (int l = tid; l < 576; l += 256) ws_[l] = w[l];
    if (tid < 64) bs_[tid] = bias[tid];
    for (int l = tid; l < 9 * 130; l += 256) {
        int r = l / 130, c = l - r * 130;
        int ih = 2 * oh0 - 1 + r;
        int iw = c - 1;
        float v = 0.f;
        if ((unsigned)ih < 256u && (unsigned)iw < 128u)
            v = d[(b * 256 + ih) * 128 + iw];
        in_s[r][c] = v;
    }
    __syncthreads();

    int ocg = tid & 7;
#pragma unroll
    for (int pb = 0; pb < 8; ++pb) {
        int pos = pb * 32 + (tid >> 3);
        int ohl = pos >> 6, ow = pos & 63;
        short8 res;
#pragma unroll
        for (int j = 0; j < 8; ++j) {
            int oc = ocg * 8 + j;
            float a = bs_[oc];
#pragma unroll
            for (int kh = 0; kh < 3; ++kh)
#pragma unroll
                for (int kw = 0; kw < 3; ++kw)
                    a = fmaf(in_s[2 * ohl + kh][2 * ow + kw],
                             ws_[oc * 9 + kh * 3 + kw], a);
            union { __hip_bfloat16 h; short s; } u;
            u.h = __float2bfloat16(a);
            res[j] = u.s;
        }
        long gpos = ((long)(b * 128 + oh0 + ohl) * 64 + ow);
        *(short8*)((short*)out + gpos * 64 + ocg * 8) = res;
    }
}

// conv2 MFMA: M-tile 128, full k=64 per s, loads(s+1) pipelined under MFMA(s).
__global__ __launch_bounds__(256) void conv2_mfma(
    const __hip_bfloat16* __restrict__ in, const __hip_bfloat16* __restrict__ w2t,
    const float* __restrict__ bias, __hip_bfloat16* __restrict__ out)
{
    __shared__ short A_lds[128][72];
    __shared__ short B_lds[128][72];
    int tid = threadIdx.x;
    int oh0 = blockIdx.x * 4;
    int b   = blockIdx.y;
    int lane = tid & 63, wave = tid >> 6;
    int l16 = lane & 15, lh = lane >> 4;
    const short* inp = (const short*)in;
    const short* w2p = (const short*)w2t;

    floatx4 acc[2][8] = {};
    short8 av[4], bv[4];

#pragma unroll
    for (int i = 0; i < 4; ++i) {
        int c = tid + i * 256;
        int pos = c >> 3, seg = c & 7;
        int ohl = pos >> 5, ow = pos & 31;
        int ih = 2 * (oh0 + ohl) - 1;
        int iw = 2 * ow - 1;
        short8 v = {0,0,0,0,0,0,0,0};
        if ((unsigned)ih < 128u && (unsigned)iw < 64u)
            v = *(const short8*)(inp + (((long)(b * 128 + ih) * 64 + iw) * 64 + seg * 8));
        av[i] = v;
        bv[i] = *(const short8*)(w2p + pos * 576 + seg * 8);
    }

    for (int s = 0; s < 9; ++s) {
        __syncthreads();
#pragma unroll
        for (int i = 0; i < 4; ++i) {
            int c = tid + i * 256;
            int pos = c >> 3, seg = c & 7;
            *(short8*)&A_lds[pos][seg * 8] = av[i];
            *(short8*)&B_lds[pos][seg * 8] = bv[i];
        }
        __syncthreads();
        if (s < 8) {
            int sn = s + 1;
            int kh = sn / 3, kw = sn - kh * 3;
#pragma unroll
            for (int i = 0; i < 4; ++i) {
                int c = tid + i * 256;
                int pos = c >> 3, seg = c & 7;
                int ohl = pos >> 5, ow = pos & 31;
                int ih = 2 * (oh0 + ohl) - 1 + kh;
                int iw = 2 * ow - 1 + kw;
                short8 v = {0,0,0,0,0,0,0,0};
                if ((unsigned)ih < 128u && (unsigned)iw < 64u)
                    v = *(const short8*)(inp + (((long)(b * 128 + ih) * 64 + iw) * 64 + seg * 8));
                av[i] = v;
                bv[i] = *(const short8*)(w2p + pos * 576 + sn * 64 + seg * 8);
            }
        }
#pragma unroll
        for (int half = 0; half < 2; ++half) {
            short8 a0 = *(const short8*)&A_lds[wave * 32 + l16][half * 32 + lh * 8];
            short8 a1 = *(const short8*)&A_lds[wave * 32 + 16 + l16][half * 32 + lh * 8];
#pragma unroll
            for (int ni = 0; ni < 8; ++ni) {
                short8 bvf = *(const short8*)&B_lds[ni * 16 + l16][half * 32 + lh * 8];
                acc[0][ni] = MFMA16(a0, bvf, acc[0][ni]);
                acc[1][ni] = MFMA16(a1, bvf, acc[1][ni]);
            }
        }
    }

    float bf[8];
#pragma unroll
    for (int ni = 0; ni < 8; ++ni) bf[ni] = bias[ni * 16 + l16];
#pragma unroll
    for (int mi = 0; mi < 2; ++mi)
#pragma unroll
        for (int r = 0; r < 4; ++r) {
            int m = wave * 32 + mi * 16 + lh * 4 + r;
            int ohl = m >> 5, ow = m & 31;
            __hip_bfloat16* op = out + (((long)(b * 64 + oh0 + ohl) * 32) + ow) * 128;
#pragma unroll
            for (int ni = 0; ni < 8; ++ni) {
                int oc = ni * 16 + l16;
                op[oc] = __float2bfloat16(acc[mi][ni][r] + bf[ni]);
            }
        }
}

// conv3 MFMA + fused v-GEMM, loads(s+1) pipelined under MFMA(s).
__global__ __launch_bounds__(256) void conv3_mfma(
    const __hip_bfloat16* __restrict__ in, const __hip_bfloat16* __restrict__ w3t,
    const float* __restrict__ bias, const __hip_bfloat16* __restrict__ Bh,
    const __hip_bfloat16* __restrict__ Bl, const float* __restrict__ c0v,
    float* __restrict__ v)
{
    __shared__ short A_lds[64][136];
    __shared__ short B_lds[128][136];
    int tid = threadIdx.x;
    int oh0 = blockIdx.x * 4;
    int b   = blockIdx.y;
    int lane = tid & 63, wave = tid >> 6;
    int wr = wave >> 1, wc = wave & 1;
    int l16 = lane & 15, lh = lane >> 4;
    const short* inp = (const short*)in;
    const short* w3p = (const short*)w3t;

    floatx4 acc[2][4] = {};
    short8 av[4], bv[8];

#pragma unroll
    for (int i = 0; i < 4; ++i) {
        int c = tid + i * 256;
        int pos = c >> 4, seg = c & 15;
        int oa = pos >> 4, ow = pos & 15;
        int ih = 2 * (oh0 + oa) - 1;
        int iw = 2 * ow - 1;
        short8 vv = {0,0,0,0,0,0,0,0};
        if ((unsigned)ih < 64u && (unsigned)iw < 32u)
            vv = *(const short8*)(inp + (((long)(b * 64 + ih) * 32 + iw) * 128 + seg * 8));
        av[i] = vv;
    }
#pragma unroll
    for (int i = 0; i < 8; ++i) {
        int c = tid + i * 256;
        int oc = c >> 4, seg = c & 15;
        bv[i] = *(const short8*)(w3p + oc * 1152 + seg * 8);
    }

    for (int s = 0; s < 9; ++s) {
        __syncthreads();
#pragma unroll
        for (int i = 0; i < 4; ++i) {
            int c = tid + i * 256;
            int pos = c >> 4, seg = c & 15;
            *(short8*)&A_lds[pos][seg * 8] = av[i];
        }
#pragma unroll
        for (int i = 0; i < 8; ++i) {
            int c = tid + i * 256;
            int oc = c >> 4, seg = c & 15;
            *(short8*)&B_lds[oc][seg * 8] = bv[i];
        }
        __syncthreads();
        if (s < 8) {
            int sn = s + 1;
            int kh = sn / 3, kw = sn - kh * 3;
#pragma unroll
            for (int i = 0; i < 4; ++i) {
                int c = tid + i * 256;
                int pos = c >> 4, seg = c & 15;
                int oa = pos >> 4, ow = pos & 15;
                int ih = 2 * (oh0 + oa) - 1 + kh;
                int iw = 2 * ow - 1 + kw;
                short8 vv = {0,0,0,0,0,0,0,0};
                if ((unsigned)ih < 64u && (unsigned)iw < 32u)
                    vv = *(const short8*)(inp + (((long)(b * 64 + ih) * 32 + iw) * 128 + seg * 8));
                av[i] = vv;
            }
#pragma unroll
            for (int i = 0; i < 8; ++i) {
                int c = tid + i * 256;
                int oc = c >> 4, seg = c & 15;
                bv[i] = *(const short8*)(w3p + oc * 1152 + sn * 128 + seg * 8);
            }
        }
#pragma unroll
        for (int ks = 0; ks < 4; ++ks) {
            short8 a0 = *(const short8*)&A_lds[wr * 32 + l16][ks * 32 + lh * 8];
            short8 a1 = *(const short8*)&A_lds[wr * 32 + 16 + l16][ks * 32 + lh * 8];
#pragma unroll
            for (int ni = 0; ni < 4; ++ni) {
                short8 bvf = *(const short8*)&B_lds[wc * 64 + ni * 16 + l16][ks * 32 + lh * 8];
                acc[0][ni] = MFMA16(a0, bvf, acc[0][ni]);
                acc[1][ni] = MFMA16(a1, bvf, acc[1][ni]);
            }
        }
    }

    float bf[4];
#pragma unroll
    for (int ni = 0; ni < 4; ++ni) bf[ni] = bias[wc * 64 + ni * 16 + l16];

    __syncthreads();
    short (*Dh)[136] = A_lds;
    short (*Dl)[136] = B_lds;
#pragma unroll
    for (int mi = 0; mi < 2; ++mi)
#pragma unroll
        for (int r = 0; r < 4; ++r) {
            int m = wr * 32 + mi * 16 + lh * 4 + r;
#pragma unroll
            for (int ni = 0; ni < 4; ++ni) {
                int oc = wc * 64 + ni * 16 + l16;
                float f = acc[mi][ni][r] + bf[ni];
                union { __hip_bfloat16 bb; short ss; } uh, ul;
                uh.bb = __float2bfloat16(f);
                ul.bb = __float2bfloat16(f - __bfloat162float(uh.bb));
                Dh[m][oc] = uh.ss;
                Dl[m][oc] = ul.ss;
            }
        }
    __syncthreads();

    floatx4 vacc[2][4] = {};
#pragma unroll
    for (int kk = 0; kk < 4; ++kk) {
        short8 ah[2], al[2];
#pragma unroll
        for (int mi = 0; mi < 2; ++mi) {
            ah[mi] = *(const short8*)&Dh[wr * 32 + mi * 16 + l16][kk * 32 + lh * 8];
            al[mi] = *(const short8*)&Dl[wr * 32 + mi * 16 + l16][kk * 32 + lh * 8];
        }
#pragma unroll
        for (int nf = 0; nf < 4; ++nf) {
            int gn = wc * 64 + nf * 16 + l16;
            short8 bh = *(const short8*)((const short*)Bh + gn * 128 + kk * 32 + lh * 8);
            short8 bl = *(const short8*)((const short*)Bl + gn * 128 + kk * 32 + lh * 8);
#pragma unroll
            for (int mi = 0; mi < 2; ++mi) {
                vacc[mi][nf] = MFMA16(ah[mi], bh, vacc[mi][nf]);
                vacc[mi][nf] = MFMA16(al[mi], bh, vacc[mi][nf]);
                vacc[mi][nf] = MFMA16(ah[mi], bl, vacc[mi][nf]);
            }
        }
    }
#pragma unroll
    for (int nf = 0; nf < 4; ++nf) {
        int gn = wc * 64 + nf * 16 + l16;
        float cv = c0v[gn];
#pragma unroll
        for (int mi = 0; mi < 2; ++mi)
#pragma unroll
            for (int r = 0; r < 4; ++r) {
                int m = wr * 32 + mi * 16 + lh * 4 + r;
                v[((long)(b * 512 + oh0 * 16 + m)) * 128 + gn] = vacc[mi][nf][r] + cv;
            }
    }
}

// selbw: MFMA hi/lo GEMM + sigmoid + softmax + bw, K-chunk loads pipelined.
__global__ __launch_bounds__(256) void selbw_k(
    const float* __restrict__ F, const __hip_bfloat16* __restrict__ Wbh,
    const __hip_bfloat16* __restrict__ Wbl, const float* __restrict__ rowbias,
    int* __restrict__ idxb, float* __restrict__ wtb)
{
    __shared__ short Ah[16][136];
    __shared__ short Al[16][136];
    __shared__ float slx[16][24], sly[16][24], satt[16][24];
    int tid = threadIdx.x;
    int m0 = blockIdx.x * 16;
    int padd = (m0 >> 7) + 1;
    int lane = tid & 63, wave = tid >> 6;
    int l16 = lane & 15, lh = lane >> 4;

    int sr = tid >> 4, sc = (tid & 15) * 8;
    const float* fsrc = F + (long)(m0 + sr + padd) * 768 + sc;

    floatx4 acc0 = {0.f, 0.f, 0.f, 0.f};
    floatx4 acc1 = {0.f, 0.f, 0.f, 0.f};
    bool two = (wave == 3);
    const short* bhp = (const short*)Wbh;
    const short* blp = (const short*)Wbl;
    int gn0 = wave * 16 + l16;
    int gn1 = 64 + l16;

    float4 f0 = *(const float4*)(fsrc);
    float4 f1 = *(const float4*)(fsrc + 4);

    for (int c = 0; c < 6; ++c) {
        shortx4 h0, l0, h1, l1;
#pragma unroll
        for (int i = 0; i < 4; ++i) {
            union { __hip_bfloat16 b; short s; } uh, ul;
            float fa = (&f0.x)[i];
            uh.b = __float2bfloat16(fa);
            ul.b = __float2bfloat16(fa - __bfloat162float(uh.b));
            h0[i] = uh.s; l0[i] = ul.s;
            float fb = (&f1.x)[i];
            uh.b = __float2bfloat16(fb);
            ul.b = __float2bfloat16(fb - __bfloat162float(uh.b));
            h1[i] = uh.s; l1[i] = ul.s;
        }
        __syncthreads();
        *(shortx4*)&Ah[sr][sc]     = h0;
        *(shortx4*)&Ah[sr][sc + 4] = h1;
        *(shortx4*)&Al[sr][sc]     = l0;
        *(shortx4*)&Al[sr][sc + 4] = l1;
        __syncthreads();
        if (c < 5) {
            f0 = *(const float4*)(fsrc + (c + 1) * 128);
            f1 = *(const float4*)(fsrc + (c + 1) * 128 + 4);
        }
#pragma unroll
        for (int ks = 0; ks < 4; ++ks) {
            short8 ah = *(const short8*)&Ah[l16][ks * 32 + lh * 8];
            short8 al = *(const short8*)&Al[l16][ks * 32 + lh * 8];
            int koff = c * 128 + ks * 32 + lh * 8;
            short8 bh0 = *(const short8*)(bhp + gn0 * 768 + koff);
            short8 bl0 = *(const short8*)(blp + gn0 * 768 + koff);
            acc0 = MFMA16(ah, bh0, acc0);
            acc0 = MFMA16(al, bh0, acc0);
            acc0 = MFMA16(ah, bl0, acc0);
            if (two) {
                short8 bh1 = *(const short8*)(bhp + gn1 * 768 + koff);
                short8 bl1 = *(const short8*)(blp + gn1 * 768 + koff);
                acc1 = MFMA16(ah, bh1, acc1);
                acc1 = MFMA16(al, bh1, acc1);
                acc1 = MFMA16(ah, bl1, acc1);
            }
        }
    }

    if (wave < 3) {
        int j = wave * 16 + l16;
#pragma unroll
        for (int r = 0; r < 4; ++r) {
            int rl = lh * 4 + r;
            float val = acc0[r] + rowbias[((m0 + rl) >> 7) * 72 + j];
            float sg = 1.f / (1.f + expf(-val));
            if (j & 1) sly[rl][j >> 1] = sg;
            else       slx[rl][j >> 1] = sg;
        }
    } else {
#pragma unroll
        for (int r = 0; r < 4; ++r) {
            int rl = lh * 4 + r;
            int b72 = ((m0 + rl) >> 7) * 72;
            float s0 = 1.f / (1.f + expf(-(acc0[r] + rowbias[b72 + 48 + l16])));
            float s1 = -1e30f;
            if (l16 < 8)
                s1 = 1.f / (1.f + expf(-(acc1[r] + rowbias[b72 + 64 + l16])));
            float mx = fmaxf(s0, s1);
#pragma unroll
            for (int s = 1; s < 16; s <<= 1)
                mx = fmaxf(mx, __shfl_xor(mx, s));
            float e0 = expf(s0 - mx);
            float e1 = (l16 < 8) ? expf(s1 - mx) : 0.f;
            float sum = e0 + e1;
#pragma unroll
            for (int s = 1; s < 16; s <<= 1)
                sum += __shfl_xor(sum, s);
            satt[rl][l16] = e0 / sum;
            if (l16 < 8) satt[rl][16 + l16] = e1 / sum;
        }
    }
    __syncthreads();

    for (int e = tid; e < 384; e += 256) {
        int rl = e / 24, k = e - rl * 24;
        int row = m0 + rl;
        float lxv = slx[rl][k], lyv = sly[rl][k];
        float a = satt[rl][k] * (1.f / 24.f);
        float x1 = floorf(lxv * 15.f), x2 = fminf(x1 + 1.f, 15.f);
        float y1 = floorf(lyv * 31.f), y2 = fminf(y1 + 1.f, 31.f);
        int xi1 = (int)x1, xi2 = (int)x2, yi1 = (int)y1, yi2 = (int)y2;
        float x = lxv * 16.f, y = lyv * 32.f;
        float w_ = x2 - x1, h_ = y2 - y1;
        float hwp = h_ * w_;
        bool deg = (h_ == 0.f) || (w_ == 0.f);
        float denom = (hwp == 0.f) ? 1.f : hwp;
        float coeff = (deg ? 2.f : 1.f / denom) * a;
        float xv0 = (w_ == 0.f) ? 1.f : (x2 - x);
        float xv1 = (w_ == 0.f) ? 1.f : (x - x1);
        float yv0 = (h_ == 0.f) ? 1.f : (y2 - y);
        float yv1 = (h_ == 0.f) ? 1.f : (y - y1);
        intx4 iv; floatx4 wv;
        iv[0] = (xi1 * 16 + yi2) * 128;
        iv[1] = (xi2 * 16 + yi2) * 128;
        iv[2] = (xi2 * 16 + yi1) * 128;
        iv[3] = (xi1 * 16 + yi1) * 128;
        wv[0] = coeff * xv0 * yv0;
        wv[1] = coeff * xv0 * yv1;
        wv[2] = coeff * xv1 * yv0;
        wv[3] = coeff * xv1 * yv1;
        *(intx4*)&idxb[(long)row * 96 + k * 4] = iv;
        *(floatx4*)&wtb[(long)row * 96 + k * 4] = wv;
    }
}

// r2d, LDS-resident v: block = (ch-sixteenth cq, b). vs[512][20] padded.
// v read from HBM exactly once; gathers served from LDS. Same FMA order.
__global__ __launch_bounds__(256) void r2d_k(
    const float* __restrict__ v, const int* __restrict__ idxb,
    const float* __restrict__ wtb, float* __restrict__ r2d)
{
    __shared__ float vs[512][20];      // 40,960 B; stride 20 floats: 16B-aligned
    __shared__ int  sidx[16][96];      // 6,144 B
    __shared__ float swt[16][96];      // 6,144 B  (total 53.2 KB)
    int cq = blockIdx.x;               // 0..7
    int b  = blockIdx.y;
    int tid = threadIdx.x;

    const float* vbase = v + (long)b * 65536 + cq * 16;
    for (int f = tid; f < 2048; f += 256) {      // 512 pos x 4 float4
        int pos = f >> 2, fc = (f & 3) * 4;
        float4 t4 = *(const float4*)(vbase + (long)pos * 128 + fc);
        *(float4*)&vs[pos][fc] = t4;
    }

    int cc = tid & 15, rr = tid >> 4;  // 16 ch x 16 rows
    const float* vf = &vs[0][0];
    for (int ch = 0; ch < 8; ++ch) {   // 8 chunks of 16 rows
        __syncthreads();               // (first iter: also covers v staging)
        for (int l = tid; l < 16 * 96; l += 256) {
            int r = l / 96, e = l - r * 96;
            long base = ((long)(b * 128 + ch * 16 + r)) * 96 + e;
            sidx[r][e] = (idxb[base] >> 7) * 20;   // LDS row offset
            swt[r][e]  = wtb[base];
        }
        __syncthreads();
        const int* si = sidx[rr];
        const float* sw = swt[rr];
        float acc = 0.f;
#pragma unroll
        for (int k = 0; k < 24; ++k) {
            float v0 = vf[si[k * 4 + 0] + cc];
            float v1 = vf[si[k * 4 + 1] + cc];
            float v2 = vf[si[k * 4 + 2] + cc];
            float v3 = vf[si[k * 4 + 3] + cc];
            acc = fmaf(sw[k * 4 + 0], v0, acc);
            acc = fmaf(sw[k * 4 + 1], v1, acc);
            acc = fmaf(sw[k * 4 + 2], v2, acc);
            acc = fmaf(sw[k * 4 + 3], v3, acc);
        }
        r2d[((long)(b * 128 + ch * 16 + rr)) * 128 + cq * 16 + cc] = acc;
    }
}

// fecls: fe = mean over n of r2d, then cls = fe @ W_cls.
__global__ __launch_bounds__(256) void fecls_k(
    const float* __restrict__ r2d, const float* __restrict__ W_cls,
    float* __restrict__ out)
{
    __shared__ float fe_s[128];
    int b = blockIdx.x, t = threadIdx.x;
    if (t < 128) {
        float acc = 0.f;
        for (int nn = 0; nn < 128; ++nn)
            acc += r2d[((long)b * 128 + nn) * 128 + t];
        acc *= (1.f / 128.f);
        fe_s[t] = acc;
        out[64 * 751 + b * 128 + t] = acc;
    }
    __syncthreads();
    for (int j = t; j < 751; j += 256) {
        float acc = 0.f;
        for (int k = 0; k < 128; ++k)
            acc = fmaf(fe_s[k], W_cls[k * 751 + j], acc);
        out[b * 751 + j] = acc;
    }
}

extern "C" void kernel_launch(void* const* d_in, const int* in_sizes, int n_in,
                              void* d_out, int out_size, void* d_ws, size_t ws_size,
                              hipStream_t stream)
{
    const float* features = (const float*)d_in[0];
    const float* d        = (const float*)d_in[1];
    const float* W_rg  = (const float*)d_in[2];
    const float* b_rg  = (const float*)d_in[3];
    const float* W_rl  = (const float*)d_in[4];
    const float* b_rl  = (const float*)d_in[5];
    const float* c1w   = (const float*)d_in[6];
    const float* c1b   = (const float*)d_in[7];
    const float* c2w   = (const float*)d_in[8];
    const float* c2b   = (const float*)d_in[9];
    const float* c3w   = (const float*)d_in[10];
    const float* c3b   = (const float*)d_in[11];
    const float* g_depth = (const float*)d_in[12];
    const float* W_merge = (const float*)d_in[13];
    const float* b_merge = (const float*)d_in[14];
    const float* W_q   = (const float*)d_in[15];
    const float* b_q   = (const float*)d_in[16];
    const float* W_v   = (const float*)d_in[17];
    const float* b_v   = (const float*)d_in[18];
    const float* W_sel = (const float*)d_in[19];
    const float* b_sel = (const float*)d_in[20];
    const float* W_cls = (const float*)d_in[21];
    float* out = (float*)d_out;

    char* ws = (char*)d_ws;
    __hip_bfloat16* c1 = (__hip_bfloat16*)(ws + 0);            // NHWC, ws[0 .. 67,108,864)
    float* v      = (float*)(ws + 33554432);                   // 16,777,216 (inside c1, written post-conv2)
    __hip_bfloat16* c2 = (__hip_bfloat16*)(ws + 67108864);     // NHWC 33,554,432
    __hip_bfloat16* w2t = (__hip_bfloat16*)(ws + 100663296);          // 147,456
    __hip_bfloat16* w3t = (__hip_bfloat16*)(ws + 100810752);          // 294,912
    // folded-weight buffers: dead gap, untouched by convs
    float* W_qs    = (float*)(ws + 101105664);                 // 73,728
    float* W_mv    = (float*)(ws + 101179392);                 // 65,536
    float* W_big   = (float*)(ws + 101244928);                 // 221,184
    float* rowbias = (float*)(ws + 101466112);                 // 18,432
    float* c0b     = (float*)(ws + 101484544);                 // 512
    float* c0v     = (float*)(ws + 101485056);                 // 512
    float* gfeat   = (float*)(ws + 101485568);                 // 32,768
    __hip_bfloat16* Wmv_bh = (__hip_bfloat16*)(ws + 101518336);  // 32,768
    __hip_bfloat16* Wmv_bl = (__hip_bfloat16*)(ws + 101551104);  // 32,768
    __hip_bfloat16* Wbig_h = (__hip_bfloat16*)(ws + 101583872);  // 122,880
    __hip_bfloat16* Wbig_l = (__hip_bfloat16*)(ws + 101706752);  // 122,880 (ends 101,829,632)
    int*   idxb   = (int*)(ws + 101832704);                    // 3,145,728
    float* wtb    = (float*)(ws + 104978432);                  // 3,145,728 (ends 108,124,160)
    float* r2d    = (float*)(ws + 113836544);                  // 4,194,304

    // ---- prep (folded weights), 3 launches ----
    prep_a<<<1129, 256, 0, stream>>>(W_q, W_sel, W_merge, W_v, g_depth, b_merge,
                                     features, W_rg, b_rg, c2w, c3w,
                                     W_qs, W_mv, c0b, gfeat, w2t, w3t);
    prep2_k<<<289, 256, 0, stream>>>(W_rl, W_qs, W_sel, b_rl, b_q, b_sel,
                                     gfeat, c0b, W_v, b_v, W_big, rowbias, c0v);
    prep_b<<<304, 256, 0, stream>>>(W_mv, W_big, Wmv_bh, Wmv_bl, Wbig_h, Wbig_l);

    // ---- conv path (MFMA) ----
    conv1_k<<<2048, 256, 0, stream>>>(d, c1w, c1b, c1);
    conv2_mfma<<<dim3(16, 64), 256, 0, stream>>>(c1, w2t, c2b, c2);
    // conv3 + v-GEMM fused
    conv3_mfma<<<dim3(8, 64), 256, 0, stream>>>(c2, w3t, c3b,
                                                Wmv_bh, Wmv_bl, c0v, v);

    // sel GEMM + sigmoid + softmax + bilinear-weight precompute (fused)
    selbw_k<<<512, 256, 0, stream>>>(features, Wbig_h, Wbig_l, rowbias,
                                     idxb, wtb);

    // ---- fusion tail ----
    r2d_k<<<dim3(8, 64), 256, 0, stream>>>(v, idxb, wtb, r2d);
    fecls_k<<<64, 256, 0, stream>>>(r2d, W_cls, out);
}

// Round 21
// 204.182 us; speedup vs baseline: 1.0813x; 1.0813x over previous
//
#include <hip/hip_runtime.h>
#include <hip/hip_bf16.h>

// ---------------------------------------------------------------------------
// FourDNet forward. Convs = bf16 MFMA implicit GEMM (NHWC). Folded chain:
//   v   = dep @ (W_merge_bot @ W_v) + c0v   [fused INTO conv3]
//   sel = sigmoid(F[:,1:] @ W_big + rowbias[b])  [MFMA hi/lo + fused bw]
// Round 21: REVERT r2d to round-18 MLP edition (global gathers, 16x64 grid).
//   r19/r20's LDS-resident r2d regressed +16us (LDS gather bank conflicts +
//   2-blk/CU occupancy loss + 8x redundant v staging). r18 config = best
//   measured (204.7us). Everything else unchanged from r18.
// ---------------------------------------------------------------------------

typedef __attribute__((ext_vector_type(8))) short short8;
typedef __attribute__((ext_vector_type(4))) short shortx4;
typedef __attribute__((ext_vector_type(4))) float floatx4;
typedef __attribute__((ext_vector_type(4))) int intx4;

#define MFMA16(a, b, c) __builtin_amdgcn_mfma_f32_16x16x32_bf16(a, b, c, 0, 0, 0)

// ---- prep_a: [0,72) W_qs, [72,200) W_mv, 200 c0, (200,265) gfeat,
//              [265,553) wt2, [553,1129) wt3 ----
__global__ __launch_bounds__(256) void prep_a(
    const float* __restrict__ W_q, const float* __restrict__ W_sel,
    const float* __restrict__ W_merge, const float* __restrict__ W_v,
    const float* __restrict__ g_depth, const float* __restrict__ b_merge,
    const float* __restrict__ features, const float* __restrict__ W_rg,
    const float* __restrict__ b_rg, const float* __restrict__ c2w,
    const float* __restrict__ c3w,
    float* __restrict__ W_qs, float* __restrict__ W_mv,
    float* __restrict__ c0, float* __restrict__ gfeat,
    __hip_bfloat16* __restrict__ w2t, __hip_bfloat16* __restrict__ w3t)
{
    __shared__ float fr_s[768];
    int bid = blockIdx.x, t = threadIdx.x;
    if (bid < 72) {
        int j = bid;
        float acc = 0.f;
        for (int k = 0; k < 128; ++k)
            acc = fmaf(W_q[t * 128 + k], W_sel[k * 72 + j], acc);
        W_qs[t * 72 + j] = acc;
    } else if (bid < 200) {
        int j = bid - 72;
        if (t < 128) {
            float acc = 0.f;
            for (int k = 0; k < 128; ++k)
                acc = fmaf(W_merge[(128 + t) * 128 + k], W_v[k * 128 + j], acc);
            W_mv[t * 128 + j] = acc;
        }
    } else if (bid == 200) {
        if (t < 128) {
            float acc = b_merge[t];
            for (int k = 0; k < 128; ++k)
                acc = fmaf(g_depth[k], W_merge[k * 128 + t], acc);
            c0[t] = acc;
        }
    } else if (bid < 265) {               // gfeat row = bid-201 (64 rows)
        int row = bid - 201;
        for (int l = t; l < 768; l += 256)
            fr_s[l] = features[(long)row * 129 * 768 + l];
        __syncthreads();
        if (t < 128) {
            float acc = b_rg[t];
            for (int k = 0; k < 768; ++k)
                acc = fmaf(fr_s[k], W_rg[k * 128 + t], acc);
            gfeat[row * 128 + t] = acc;
        }
    } else if (bid < 553) {               // wt2
        int idx = (bid - 265) * 256 + t;
        if (idx < 128 * 576) {
            int oc = idx / 576, k = idx % 576;
            int s = k >> 6, ic = k & 63;
            w2t[idx] = __float2bfloat16(c2w[oc * 576 + ic * 9 + s]);
        }
    } else {                              // wt3
        int idx = (bid - 553) * 256 + t;
        if (idx < 128 * 1152) {
            int oc = idx / 1152, k = idx % 1152;
            int s = k >> 7, ic = k & 127;
            w3t[idx] = __float2bfloat16(c3w[oc * 1152 + ic * 9 + s]);
        }
    }
}

// ---- prep2: W_big [768][72], rowbias [64][72], c0v [128] ----
__global__ __launch_bounds__(256) void prep2_k(
    const float* __restrict__ W_rl, const float* __restrict__ W_qs,
    const float* __restrict__ W_sel, const float* __restrict__ b_rl,
    const float* __restrict__ b_q, const float* __restrict__ b_sel,
    const float* __restrict__ gfeat, const float* __restrict__ c0,
    const float* __restrict__ W_v, const float* __restrict__ b_v,
    float* __restrict__ W_big, float* __restrict__ rowbias,
    float* __restrict__ c0v)
{
    int bid = blockIdx.x, t = threadIdx.x;
    if (bid < 216) {
        int j = bid / 3;
        int i = (bid % 3) * 256 + t;
        float acc = 0.f;
        for (int k = 0; k < 128; ++k)
            acc = fmaf(W_rl[i * 128 + k], W_qs[(128 + k) * 72 + j], acc);
        W_big[i * 72 + j] = acc;
    } else if (bid < 288) {
        int j = bid - 216;
        if (t < 64) {
            float vb = b_sel[j];
            for (int k = 0; k < 128; ++k) {
                vb = fmaf(b_rl[k], W_qs[(128 + k) * 72 + j], vb);
                vb = fmaf(b_q[k], W_sel[k * 72 + j], vb);
            }
            float acc = vb;
            for (int k = 0; k < 128; ++k)
                acc = fmaf(gfeat[t * 128 + k], W_qs[k * 72 + j], acc);
            rowbias[t * 72 + j] = acc;
        }
    } else {
        if (t < 128) {
            float acc = b_v[t];
            for (int k = 0; k < 128; ++k)
                acc = fmaf(c0[k], W_v[k * 128 + t], acc);
            c0v[t] = acc;
        }
    }
}

// ---- prep_b: [0,64) W_mv->hi/lo, [64,304) W_big->hi/lo [80][768] ----
__global__ __launch_bounds__(256) void prep_b(
    const float* __restrict__ W_mv, const float* __restrict__ W_big,
    __hip_bfloat16* __restrict__ Bh, __hip_bfloat16* __restrict__ Bl,
    __hip_bfloat16* __restrict__ Wbh, __hip_bfloat16* __restrict__ Wbl)
{
    int bid = blockIdx.x, t = threadIdx.x;
    if (bid < 64) {
        int idx = bid * 256 + t;          // 16384
        int n = idx >> 7, k = idx & 127;
        float w = W_mv[k * 128 + n];
        __hip_bfloat16 h = __float2bfloat16(w);
        Bh[idx] = h;
        Bl[idx] = __float2bfloat16(w - __bfloat162float(h));
    } else {
        int idx = (bid - 64) * 256 + t;   // 61440
        if (idx < 80 * 768) {
            int n = idx / 768, k = idx - n * 768;
            float w = (n < 72) ? W_big[k * 72 + n] : 0.f;
            __hip_bfloat16 h = __float2bfloat16(w);
            Wbh[idx] = h;
            Wbl[idx] = __float2bfloat16(w - __bfloat162float(h));
        }
    }
}

// conv1: d (64,1,256,128) f32 -> out NHWC (64,128,64,64) bf16. stride2 pad1.
__global__ __launch_bounds__(256) void conv1_k(
    const float* __restrict__ d, const float* __restrict__ w,
    const float* __restrict__ bias, __hip_bfloat16* __restrict__ out)
{
    __shared__ float in_s[9][130];
    __shared__ float ws_[576];
    __shared__ float bs_[64];
    int tid = threadIdx.x;
    int ohg = blockIdx.x & 31;
    int b   = blockIdx.x >> 5;
    int oh0 = ohg * 4;

    for (int l = tid; l < 576; l += 256) ws_[l] = w[l];
    if (tid < 64) bs_[tid] = bias[tid];
    for (int l = tid; l < 9 * 130; l += 256) {
        int r = l / 130, c = l - r * 130;
        int ih = 2 * oh0 - 1 + r;
        int iw = c - 1;
        float v = 0.f;
        if ((unsigned)ih < 256u && (unsigned)iw < 128u)
            v = d[(b * 256 + ih) * 128 + iw];
        in_s[r][c] = v;
    }
    __syncthreads();

    int ocg = tid & 7;
#pragma unroll
    for (int pb = 0; pb < 8; ++pb) {
        int pos = pb * 32 + (tid >> 3);
        int ohl = pos >> 6, ow = pos & 63;
        short8 res;
#pragma unroll
        for (int j = 0; j < 8; ++j) {
            int oc = ocg * 8 + j;
            float a = bs_[oc];
#pragma unroll
            for (int kh = 0; kh < 3; ++kh)
#pragma unroll
                for (int kw = 0; kw < 3; ++kw)
                    a = fmaf(in_s[2 * ohl + kh][2 * ow + kw],
                             ws_[oc * 9 + kh * 3 + kw], a);
            union { __hip_bfloat16 h; short s; } u;
            u.h = __float2bfloat16(a);
            res[j] = u.s;
        }
        long gpos = ((long)(b * 128 + oh0 + ohl) * 64 + ow);
        *(short8*)((short*)out + gpos * 64 + ocg * 8) = res;
    }
}

// conv2 MFMA: M-tile 128, full k=64 per s, loads(s+1) pipelined under MFMA(s).
__global__ __launch_bounds__(256) void conv2_mfma(
    const __hip_bfloat16* __restrict__ in, const __hip_bfloat16* __restrict__ w2t,
    const float* __restrict__ bias, __hip_bfloat16* __restrict__ out)
{
    __shared__ short A_lds[128][72];
    __shared__ short B_lds[128][72];
    int tid = threadIdx.x;
    int oh0 = blockIdx.x * 4;
    int b   = blockIdx.y;
    int lane = tid & 63, wave = tid >> 6;
    int l16 = lane & 15, lh = lane >> 4;
    const short* inp = (const short*)in;
    const short* w2p = (const short*)w2t;

    floatx4 acc[2][8] = {};
    short8 av[4], bv[4];

#pragma unroll
    for (int i = 0; i < 4; ++i) {
        int c = tid + i * 256;
        int pos = c >> 3, seg = c & 7;
        int ohl = pos >> 5, ow = pos & 31;
        int ih = 2 * (oh0 + ohl) - 1;
        int iw = 2 * ow - 1;
        short8 v = {0,0,0,0,0,0,0,0};
        if ((unsigned)ih < 128u && (unsigned)iw < 64u)
            v = *(const short8*)(inp + (((long)(b * 128 + ih) * 64 + iw) * 64 + seg * 8));
        av[i] = v;
        bv[i] = *(const short8*)(w2p + pos * 576 + seg * 8);
    }

    for (int s = 0; s < 9; ++s) {
        __syncthreads();
#pragma unroll
        for (int i = 0; i < 4; ++i) {
            int c = tid + i * 256;
            int pos = c >> 3, seg = c & 7;
            *(short8*)&A_lds[pos][seg * 8] = av[i];
            *(short8*)&B_lds[pos][seg * 8] = bv[i];
        }
        __syncthreads();
        if (s < 8) {
            int sn = s + 1;
            int kh = sn / 3, kw = sn - kh * 3;
#pragma unroll
            for (int i = 0; i < 4; ++i) {
                int c = tid + i * 256;
                int pos = c >> 3, seg = c & 7;
                int ohl = pos >> 5, ow = pos & 31;
                int ih = 2 * (oh0 + ohl) - 1 + kh;
                int iw = 2 * ow - 1 + kw;
                short8 v = {0,0,0,0,0,0,0,0};
                if ((unsigned)ih < 128u && (unsigned)iw < 64u)
                    v = *(const short8*)(inp + (((long)(b * 128 + ih) * 64 + iw) * 64 + seg * 8));
                av[i] = v;
                bv[i] = *(const short8*)(w2p + pos * 576 + sn * 64 + seg * 8);
            }
        }
#pragma unroll
        for (int half = 0; half < 2; ++half) {
            short8 a0 = *(const short8*)&A_lds[wave * 32 + l16][half * 32 + lh * 8];
            short8 a1 = *(const short8*)&A_lds[wave * 32 + 16 + l16][half * 32 + lh * 8];
#pragma unroll
            for (int ni = 0; ni < 8; ++ni) {
                short8 bvf = *(const short8*)&B_lds[ni * 16 + l16][half * 32 + lh * 8];
                acc[0][ni] = MFMA16(a0, bvf, acc[0][ni]);
                acc[1][ni] = MFMA16(a1, bvf, acc[1][ni]);
            }
        }
    }

    float bf[8];
#pragma unroll
    for (int ni = 0; ni < 8; ++ni) bf[ni] = bias[ni * 16 + l16];
#pragma unroll
    for (int mi = 0; mi < 2; ++mi)
#pragma unroll
        for (int r = 0; r < 4; ++r) {
            int m = wave * 32 + mi * 16 + lh * 4 + r;
            int ohl = m >> 5, ow = m & 31;
            __hip_bfloat16* op = out + (((long)(b * 64 + oh0 + ohl) * 32) + ow) * 128;
#pragma unroll
            for (int ni = 0; ni < 8; ++ni) {
                int oc = ni * 16 + l16;
                op[oc] = __float2bfloat16(acc[mi][ni][r] + bf[ni]);
            }
        }
}

// conv3 MFMA + fused v-GEMM, loads(s+1) pipelined under MFMA(s).
__global__ __launch_bounds__(256) void conv3_mfma(
    const __hip_bfloat16* __restrict__ in, const __hip_bfloat16* __restrict__ w3t,
    const float* __restrict__ bias, const __hip_bfloat16* __restrict__ Bh,
    const __hip_bfloat16* __restrict__ Bl, const float* __restrict__ c0v,
    float* __restrict__ v)
{
    __shared__ short A_lds[64][136];
    __shared__ short B_lds[128][136];
    int tid = threadIdx.x;
    int oh0 = blockIdx.x * 4;
    int b   = blockIdx.y;
    int lane = tid & 63, wave = tid >> 6;
    int wr = wave >> 1, wc = wave & 1;
    int l16 = lane & 15, lh = lane >> 4;
    const short* inp = (const short*)in;
    const short* w3p = (const short*)w3t;

    floatx4 acc[2][4] = {};
    short8 av[4], bv[8];

#pragma unroll
    for (int i = 0; i < 4; ++i) {
        int c = tid + i * 256;
        int pos = c >> 4, seg = c & 15;
        int oa = pos >> 4, ow = pos & 15;
        int ih = 2 * (oh0 + oa) - 1;
        int iw = 2 * ow - 1;
        short8 vv = {0,0,0,0,0,0,0,0};
        if ((unsigned)ih < 64u && (unsigned)iw < 32u)
            vv = *(const short8*)(inp + (((long)(b * 64 + ih) * 32 + iw) * 128 + seg * 8));
        av[i] = vv;
    }
#pragma unroll
    for (int i = 0; i < 8; ++i) {
        int c = tid + i * 256;
        int oc = c >> 4, seg = c & 15;
        bv[i] = *(const short8*)(w3p + oc * 1152 + seg * 8);
    }

    for (int s = 0; s < 9; ++s) {
        __syncthreads();
#pragma unroll
        for (int i = 0; i < 4; ++i) {
            int c = tid + i * 256;
            int pos = c >> 4, seg = c & 15;
            *(short8*)&A_lds[pos][seg * 8] = av[i];
        }
#pragma unroll
        for (int i = 0; i < 8; ++i) {
            int c = tid + i * 256;
            int oc = c >> 4, seg = c & 15;
            *(short8*)&B_lds[oc][seg * 8] = bv[i];
        }
        __syncthreads();
        if (s < 8) {
            int sn = s + 1;
            int kh = sn / 3, kw = sn - kh * 3;
#pragma unroll
            for (int i = 0; i < 4; ++i) {
                int c = tid + i * 256;
                int pos = c >> 4, seg = c & 15;
                int oa = pos >> 4, ow = pos & 15;
                int ih = 2 * (oh0 + oa) - 1 + kh;
                int iw = 2 * ow - 1 + kw;
                short8 vv = {0,0,0,0,0,0,0,0};
                if ((unsigned)ih < 64u && (unsigned)iw < 32u)
                    vv = *(const short8*)(inp + (((long)(b * 64 + ih) * 32 + iw) * 128 + seg * 8));
                av[i] = vv;
            }
#pragma unroll
            for (int i = 0; i < 8; ++i) {
                int c = tid + i * 256;
                int oc = c >> 4, seg = c & 15;
                bv[i] = *(const short8*)(w3p + oc * 1152 + sn * 128 + seg * 8);
            }
        }
#pragma unroll
        for (int ks = 0; ks < 4; ++ks) {
            short8 a0 = *(const short8*)&A_lds[wr * 32 + l16][ks * 32 + lh * 8];
            short8 a1 = *(const short8*)&A_lds[wr * 32 + 16 + l16][ks * 32 + lh * 8];
#pragma unroll
            for (int ni = 0; ni < 4; ++ni) {
                short8 bvf = *(const short8*)&B_lds[wc * 64 + ni * 16 + l16][ks * 32 + lh * 8];
                acc[0][ni] = MFMA16(a0, bvf, acc[0][ni]);
                acc[1][ni] = MFMA16(a1, bvf, acc[1][ni]);
            }
        }
    }

    float bf[4];
#pragma unroll
    for (int ni = 0; ni < 4; ++ni) bf[ni] = bias[wc * 64 + ni * 16 + l16];

    __syncthreads();
    short (*Dh)[136] = A_lds;
    short (*Dl)[136] = B_lds;
#pragma unroll
    for (int mi = 0; mi < 2; ++mi)
#pragma unroll
        for (int r = 0; r < 4; ++r) {
            int m = wr * 32 + mi * 16 + lh * 4 + r;
#pragma unroll
            for (int ni = 0; ni < 4; ++ni) {
                int oc = wc * 64 + ni * 16 + l16;
                float f = acc[mi][ni][r] + bf[ni];
                union { __hip_bfloat16 bb; short ss; } uh, ul;
                uh.bb = __float2bfloat16(f);
                ul.bb = __float2bfloat16(f - __bfloat162float(uh.bb));
                Dh[m][oc] = uh.ss;
                Dl[m][oc] = ul.ss;
            }
        }
    __syncthreads();

    floatx4 vacc[2][4] = {};
#pragma unroll
    for (int kk = 0; kk < 4; ++kk) {
        short8 ah[2], al[2];
#pragma unroll
        for (int mi = 0; mi < 2; ++mi) {
            ah[mi] = *(const short8*)&Dh[wr * 32 + mi * 16 + l16][kk * 32 + lh * 8];
            al[mi] = *(const short8*)&Dl[wr * 32 + mi * 16 + l16][kk * 32 + lh * 8];
        }
#pragma unroll
        for (int nf = 0; nf < 4; ++nf) {
            int gn = wc * 64 + nf * 16 + l16;
            short8 bh = *(const short8*)((const short*)Bh + gn * 128 + kk * 32 + lh * 8);
            short8 bl = *(const short8*)((const short*)Bl + gn * 128 + kk * 32 + lh * 8);
#pragma unroll
            for (int mi = 0; mi < 2; ++mi) {
                vacc[mi][nf] = MFMA16(ah[mi], bh, vacc[mi][nf]);
                vacc[mi][nf] = MFMA16(al[mi], bh, vacc[mi][nf]);
                vacc[mi][nf] = MFMA16(ah[mi], bl, vacc[mi][nf]);
            }
        }
    }
#pragma unroll
    for (int nf = 0; nf < 4; ++nf) {
        int gn = wc * 64 + nf * 16 + l16;
        float cv = c0v[gn];
#pragma unroll
        for (int mi = 0; mi < 2; ++mi)
#pragma unroll
            for (int r = 0; r < 4; ++r) {
                int m = wr * 32 + mi * 16 + lh * 4 + r;
                v[((long)(b * 512 + oh0 * 16 + m)) * 128 + gn] = vacc[mi][nf][r] + cv;
            }
    }
}

// selbw: MFMA hi/lo GEMM + sigmoid + softmax + bw, K-chunk loads pipelined.
__global__ __launch_bounds__(256) void selbw_k(
    const float* __restrict__ F, const __hip_bfloat16* __restrict__ Wbh,
    const __hip_bfloat16* __restrict__ Wbl, const float* __restrict__ rowbias,
    int* __restrict__ idxb, float* __restrict__ wtb)
{
    __shared__ short Ah[16][136];
    __shared__ short Al[16][136];
    __shared__ float slx[16][24], sly[16][24], satt[16][24];
    int tid = threadIdx.x;
    int m0 = blockIdx.x * 16;
    int padd = (m0 >> 7) + 1;
    int lane = tid & 63, wave = tid >> 6;
    int l16 = lane & 15, lh = lane >> 4;

    int sr = tid >> 4, sc = (tid & 15) * 8;
    const float* fsrc = F + (long)(m0 + sr + padd) * 768 + sc;

    floatx4 acc0 = {0.f, 0.f, 0.f, 0.f};
    floatx4 acc1 = {0.f, 0.f, 0.f, 0.f};
    bool two = (wave == 3);
    const short* bhp = (const short*)Wbh;
    const short* blp = (const short*)Wbl;
    int gn0 = wave * 16 + l16;
    int gn1 = 64 + l16;

    float4 f0 = *(const float4*)(fsrc);
    float4 f1 = *(const float4*)(fsrc + 4);

    for (int c = 0; c < 6; ++c) {
        shortx4 h0, l0, h1, l1;
#pragma unroll
        for (int i = 0; i < 4; ++i) {
            union { __hip_bfloat16 b; short s; } uh, ul;
            float fa = (&f0.x)[i];
            uh.b = __float2bfloat16(fa);
            ul.b = __float2bfloat16(fa - __bfloat162float(uh.b));
            h0[i] = uh.s; l0[i] = ul.s;
            float fb = (&f1.x)[i];
            uh.b = __float2bfloat16(fb);
            ul.b = __float2bfloat16(fb - __bfloat162float(uh.b));
            h1[i] = uh.s; l1[i] = ul.s;
        }
        __syncthreads();
        *(shortx4*)&Ah[sr][sc]     = h0;
        *(shortx4*)&Ah[sr][sc + 4] = h1;
        *(shortx4*)&Al[sr][sc]     = l0;
        *(shortx4*)&Al[sr][sc + 4] = l1;
        __syncthreads();
        if (c < 5) {
            f0 = *(const float4*)(fsrc + (c + 1) * 128);
            f1 = *(const float4*)(fsrc + (c + 1) * 128 + 4);
        }
#pragma unroll
        for (int ks = 0; ks < 4; ++ks) {
            short8 ah = *(const short8*)&Ah[l16][ks * 32 + lh * 8];
            short8 al = *(const short8*)&Al[l16][ks * 32 + lh * 8];
            int koff = c * 128 + ks * 32 + lh * 8;
            short8 bh0 = *(const short8*)(bhp + gn0 * 768 + koff);
            short8 bl0 = *(const short8*)(blp + gn0 * 768 + koff);
            acc0 = MFMA16(ah, bh0, acc0);
            acc0 = MFMA16(al, bh0, acc0);
            acc0 = MFMA16(ah, bl0, acc0);
            if (two) {
                short8 bh1 = *(const short8*)(bhp + gn1 * 768 + koff);
                short8 bl1 = *(const short8*)(blp + gn1 * 768 + koff);
                acc1 = MFMA16(ah, bh1, acc1);
                acc1 = MFMA16(al, bh1, acc1);
                acc1 = MFMA16(ah, bl1, acc1);
            }
        }
    }

    if (wave < 3) {
        int j = wave * 16 + l16;
#pragma unroll
        for (int r = 0; r < 4; ++r) {
            int rl = lh * 4 + r;
            float val = acc0[r] + rowbias[((m0 + rl) >> 7) * 72 + j];
            float sg = 1.f / (1.f + expf(-val));
            if (j & 1) sly[rl][j >> 1] = sg;
            else       slx[rl][j >> 1] = sg;
        }
    } else {
#pragma unroll
        for (int r = 0; r < 4; ++r) {
            int rl = lh * 4 + r;
            int b72 = ((m0 + rl) >> 7) * 72;
            float s0 = 1.f / (1.f + expf(-(acc0[r] + rowbias[b72 + 48 + l16])));
            float s1 = -1e30f;
            if (l16 < 8)
                s1 = 1.f / (1.f + expf(-(acc1[r] + rowbias[b72 + 64 + l16])));
            float mx = fmaxf(s0, s1);
#pragma unroll
            for (int s = 1; s < 16; s <<= 1)
                mx = fmaxf(mx, __shfl_xor(mx, s));
            float e0 = expf(s0 - mx);
            float e1 = (l16 < 8) ? expf(s1 - mx) : 0.f;
            float sum = e0 + e1;
#pragma unroll
            for (int s = 1; s < 16; s <<= 1)
                sum += __shfl_xor(sum, s);
            satt[rl][l16] = e0 / sum;
            if (l16 < 8) satt[rl][16 + l16] = e1 / sum;
        }
    }
    __syncthreads();

    for (int e = tid; e < 384; e += 256) {
        int rl = e / 24, k = e - rl * 24;
        int row = m0 + rl;
        float lxv = slx[rl][k], lyv = sly[rl][k];
        float a = satt[rl][k] * (1.f / 24.f);
        float x1 = floorf(lxv * 15.f), x2 = fminf(x1 + 1.f, 15.f);
        float y1 = floorf(lyv * 31.f), y2 = fminf(y1 + 1.f, 31.f);
        int xi1 = (int)x1, xi2 = (int)x2, yi1 = (int)y1, yi2 = (int)y2;
        float x = lxv * 16.f, y = lyv * 32.f;
        float w_ = x2 - x1, h_ = y2 - y1;
        float hwp = h_ * w_;
        bool deg = (h_ == 0.f) || (w_ == 0.f);
        float denom = (hwp == 0.f) ? 1.f : hwp;
        float coeff = (deg ? 2.f : 1.f / denom) * a;
        float xv0 = (w_ == 0.f) ? 1.f : (x2 - x);
        float xv1 = (w_ == 0.f) ? 1.f : (x - x1);
        float yv0 = (h_ == 0.f) ? 1.f : (y2 - y);
        float yv1 = (h_ == 0.f) ? 1.f : (y - y1);
        intx4 iv; floatx4 wv;
        iv[0] = (xi1 * 16 + yi2) * 128;
        iv[1] = (xi2 * 16 + yi2) * 128;
        iv[2] = (xi2 * 16 + yi1) * 128;
        iv[3] = (xi1 * 16 + yi1) * 128;
        wv[0] = coeff * xv0 * yv0;
        wv[1] = coeff * xv0 * yv1;
        wv[2] = coeff * xv1 * yv0;
        wv[3] = coeff * xv1 * yv1;
        *(intx4*)&idxb[(long)row * 96 + k * 4] = iv;
        *(floatx4*)&wtb[(long)row * 96 + k * 4] = wv;
    }
}

// r2d gather, MLP edition (round-18 best): 256 thr x 8 rows/block,
// k-loop fully unrolled, batched corner loads (96 independent loads/row).
__global__ __launch_bounds__(256) void r2d_k(
    const float* __restrict__ v, const int* __restrict__ idxb,
    const float* __restrict__ wtb, float* __restrict__ r2d)
{
    int rg = blockIdx.x;
    int b  = blockIdx.y;
    int tid = threadIdx.x;
    int c  = tid & 127;
    int rp = tid >> 7;
    __shared__ int sidx[8][96];
    __shared__ float swt[8][96];
    for (int l = tid; l < 8 * 96; l += 256) {
        int rr = l / 96, e = l - rr * 96;
        long base = ((long)(b * 128 + rg * 8 + rr)) * 96 + e;
        sidx[rr][e] = idxb[base];
        swt[rr][e]  = wtb[base];
    }
    __syncthreads();
    const float* vb = v + (long)b * 512 * 128 + c;
#pragma unroll
    for (int it = 0; it < 4; ++it) {
        int rr = it * 2 + rp;
        const int* si = sidx[rr];
        const float* sw = swt[rr];
        float acc = 0.f;
#pragma unroll
        for (int k = 0; k < 24; ++k) {
            float v0 = vb[si[k * 4 + 0]];
            float v1 = vb[si[k * 4 + 1]];
            float v2 = vb[si[k * 4 + 2]];
            float v3 = vb[si[k * 4 + 3]];
            acc = fmaf(sw[k * 4 + 0], v0, acc);
            acc = fmaf(sw[k * 4 + 1], v1, acc);
            acc = fmaf(sw[k * 4 + 2], v2, acc);
            acc = fmaf(sw[k * 4 + 3], v3, acc);
        }
        r2d[((long)(b * 128 + rg * 8 + rr)) * 128 + c] = acc;
    }
}

// fecls: fe = mean over n of r2d, then cls = fe @ W_cls.
__global__ __launch_bounds__(256) void fecls_k(
    const float* __restrict__ r2d, const float* __restrict__ W_cls,
    float* __restrict__ out)
{
    __shared__ float fe_s[128];
    int b = blockIdx.x, t = threadIdx.x;
    if (t < 128) {
        float acc = 0.f;
        for (int nn = 0; nn < 128; ++nn)
            acc += r2d[((long)b * 128 + nn) * 128 + t];
        acc *= (1.f / 128.f);
        fe_s[t] = acc;
        out[64 * 751 + b * 128 + t] = acc;
    }
    __syncthreads();
    for (int j = t; j < 751; j += 256) {
        float acc = 0.f;
        for (int k = 0; k < 128; ++k)
            acc = fmaf(fe_s[k], W_cls[k * 751 + j], acc);
        out[b * 751 + j] = acc;
    }
}

extern "C" void kernel_launch(void* const* d_in, const int* in_sizes, int n_in,
                              void* d_out, int out_size, void* d_ws, size_t ws_size,
                              hipStream_t stream)
{
    const float* features = (const float*)d_in[0];
    const float* d        = (const float*)d_in[1];
    const float* W_rg  = (const float*)d_in[2];
    const float* b_rg  = (const float*)d_in[3];
    const float* W_rl  = (const float*)d_in[4];
    const float* b_rl  = (const float*)d_in[5];
    const float* c1w   = (const float*)d_in[6];
    const float* c1b   = (const float*)d_in[7];
    const float* c2w   = (const float*)d_in[8];
    const float* c2b   = (const float*)d_in[9];
    const float* c3w   = (const float*)d_in[10];
    const float* c3b   = (const float*)d_in[11];
    const float* g_depth = (const float*)d_in[12];
    const float* W_merge = (const float*)d_in[13];
    const float* b_merge = (const float*)d_in[14];
    const float* W_q   = (const float*)d_in[15];
    const float* b_q   = (const float*)d_in[16];
    const float* W_v   = (const float*)d_in[17];
    const float* b_v   = (const float*)d_in[18];
    const float* W_sel = (const float*)d_in[19];
    const float* b_sel = (const float*)d_in[20];
    const float* W_cls = (const float*)d_in[21];
    float* out = (float*)d_out;

    char* ws = (char*)d_ws;
    __hip_bfloat16* c1 = (__hip_bfloat16*)(ws + 0);            // NHWC, ws[0 .. 67,108,864)
    float* v      = (float*)(ws + 33554432);                   // 16,777,216 (inside c1, written post-conv2)
    __hip_bfloat16* c2 = (__hip_bfloat16*)(ws + 67108864);     // NHWC 33,554,432
    __hip_bfloat16* w2t = (__hip_bfloat16*)(ws + 100663296);          // 147,456
    __hip_bfloat16* w3t = (__hip_bfloat16*)(ws + 100810752);          // 294,912
    // folded-weight buffers: dead gap, untouched by convs
    float* W_qs    = (float*)(ws + 101105664);                 // 73,728
    float* W_mv    = (float*)(ws + 101179392);                 // 65,536
    float* W_big   = (float*)(ws + 101244928);                 // 221,184
    float* rowbias = (float*)(ws + 101466112);                 // 18,432
    float* c0b     = (float*)(ws + 101484544);                 // 512
    float* c0v     = (float*)(ws + 101485056);                 // 512
    float* gfeat   = (float*)(ws + 101485568);                 // 32,768
    __hip_bfloat16* Wmv_bh = (__hip_bfloat16*)(ws + 101518336);  // 32,768
    __hip_bfloat16* Wmv_bl = (__hip_bfloat16*)(ws + 101551104);  // 32,768
    __hip_bfloat16* Wbig_h = (__hip_bfloat16*)(ws + 101583872);  // 122,880
    __hip_bfloat16* Wbig_l = (__hip_bfloat16*)(ws + 101706752);  // 122,880 (ends 101,829,632)
    int*   idxb   = (int*)(ws + 101832704);                    // 3,145,728
    float* wtb    = (float*)(ws + 104978432);                  // 3,145,728 (ends 108,124,160)
    float* r2d    = (float*)(ws + 113836544);                  // 4,194,304

    // ---- prep (folded weights), 3 launches ----
    prep_a<<<1129, 256, 0, stream>>>(W_q, W_sel, W_merge, W_v, g_depth, b_merge,
                                     features, W_rg, b_rg, c2w, c3w,
                                     W_qs, W_mv, c0b, gfeat, w2t, w3t);
    prep2_k<<<289, 256, 0, stream>>>(W_rl, W_qs, W_sel, b_rl, b_q, b_sel,
                                     gfeat, c0b, W_v, b_v, W_big, rowbias, c0v);
    prep_b<<<304, 256, 0, stream>>>(W_mv, W_big, Wmv_bh, Wmv_bl, Wbig_h, Wbig_l);

    // ---- conv path (MFMA) ----
    conv1_k<<<2048, 256, 0, stream>>>(d, c1w, c1b, c1);
    conv2_mfma<<<dim3(16, 64), 256, 0, stream>>>(c1, w2t, c2b, c2);
    // conv3 + v-GEMM fused
    conv3_mfma<<<dim3(8, 64), 256, 0, stream>>>(c2, w3t, c3b,
                                                Wmv_bh, Wmv_bl, c0v, v);

    // sel GEMM + sigmoid + softmax + bilinear-weight precompute (fused)
    selbw_k<<<512, 256, 0, stream>>>(features, Wbig_h, Wbig_l, rowbias,
                                     idxb, wtb);

    // ---- fusion tail ----
    r2d_k<<<dim3(16, 64), 256, 0, stream>>>(v, idxb, wtb, r2d);
    fecls_k<<<64, 256, 0, stream>>>(r2d, W_cls, out);
}